// Round 7
// baseline (24.682 us; speedup 1.0000x reference)
//
#include <hip/hip_runtime.h>

// XTermFrequency: per-row vocab frequency = histogram / rowsum.
// R6 lesson: 1-block-per-row with a 4-chunk serial loop is pinned at ~24us
// regardless of inner-loop codegen -> the limiter is the synchronized
// phase structure (2 big lockstep blocks/CU => bursty store stream).
// R7: 2D grid (row x chunk): 8 chunks of 6284 bins, 256-thread blocks,
// 25.1KB LDS -> 6 blocks/CU, 4096 independent blocks, one pass each
// (zero -> scatter -> drain), no chunk loop, no re-zero. Chunk-major
// block order puts all 8 chunks of a row on one XCD (bid%8 == r%8) so
// the 8x row re-read stays L2-resident.
#define VOCAB 50257
#define NCH   8
#define CHUNK 6284               // 8*6284 = 50272 >= VOCAB, divisible by 4
#define BLK   256

typedef float f32x4 __attribute__((ext_vector_type(4)));

// Barrier ordering LDS only; global stores/loads stay in flight.
#define LDS_BARRIER()                                            \
    do {                                                         \
        asm volatile("s_waitcnt lgkmcnt(0)" ::: "memory");       \
        __builtin_amdgcn_s_barrier();                            \
        __builtin_amdgcn_sched_barrier(0);                       \
    } while (0)

__global__ __launch_bounds__(BLK) void XTermFrequency_5471788335935_kernel(
    const int* __restrict__ asg, const float* __restrict__ w,
    float* __restrict__ out, int S, int B)
{
    __shared__ f32x4 hist4[CHUNK / 4];       // 25136 B -> 6 blocks/CU
    __shared__ float s_sum;
    float* hist = reinterpret_cast<float*>(hist4);

    const int bid = blockIdx.x;
    const int c   = bid / B;                 // chunk index (chunk-major grid)
    const int r   = bid - c * B;             // row index
    const int lo  = c * CHUNK;
    const int hi  = min(CHUNK, VOCAB - lo);  // valid bins in this chunk

    const int tid = threadIdx.x;
    const int*   __restrict__ row  = asg + (long long)r * S;
    const float* __restrict__ wrow = w   + (long long)r * S;
    float*       __restrict__ po   = out + (long long)r * VOCAB + lo;

    // ---- zero histogram + init sum ----
    const f32x4 z4 = {0.f, 0.f, 0.f, 0.f};
    for (int j = tid; j < CHUNK / 4; j += BLK) hist4[j] = z4;
    if (tid == 0) s_sum = 0.f;
    __syncthreads();

    // ---- read row (vectorized), scatter into LDS, reduce row sum ----
    float ws = 0.f;
    if ((S & 3) == 0) {
        const int4*   __restrict__ rv = reinterpret_cast<const int4*>(row);
        const float4* __restrict__ wv = reinterpret_cast<const float4*>(wrow);
        for (int q = tid; q < (S >> 2); q += BLK) {
            const int4   a4 = rv[q];
            const float4 w4 = wv[q];
            ws += (w4.x + w4.y) + (w4.z + w4.w);
            const int v0 = a4.x - lo, v1 = a4.y - lo,
                      v2 = a4.z - lo, v3 = a4.w - lo;
            if ((unsigned)v0 < (unsigned)CHUNK) atomicAdd(&hist[v0], w4.x);
            if ((unsigned)v1 < (unsigned)CHUNK) atomicAdd(&hist[v1], w4.y);
            if ((unsigned)v2 < (unsigned)CHUNK) atomicAdd(&hist[v2], w4.z);
            if ((unsigned)v3 < (unsigned)CHUNK) atomicAdd(&hist[v3], w4.w);
        }
    } else {
        for (int s = tid; s < S; s += BLK) {
            ws += wrow[s];
            const int v = row[s] - lo;
            if ((unsigned)v < (unsigned)CHUNK) atomicAdd(&hist[v], wrow[s]);
        }
    }
    // wave(64) shuffle reduce, one native ds-atomic per wave
    #pragma unroll
    for (int off = 32; off > 0; off >>= 1) ws += __shfl_down(ws, off, 64);
    if ((tid & 63) == 0) atomicAdd(&s_sum, ws);
    LDS_BARRIER();

    const float inv = 1.0f / s_sum;          // 2^-11 exact for the bench

    // ---- drain: head-align to 16B, float4 body, scalar tail ----
    const int head0 = (int)(((16u - ((unsigned)(uintptr_t)po & 15u)) & 15u) >> 2);
    const int head  = head0 < hi ? head0 : hi;
    if (tid < head) po[tid] = hist[tid] * inv;
    const int nv = (hi - head) >> 2;
    float4* __restrict__ pv = reinterpret_cast<float4*>(po + head);
    for (int j = tid; j < nv; j += BLK) {
        const int i = head + (j << 2);
        float4 h;
        h.x = hist[i]     * inv;
        h.y = hist[i + 1] * inv;
        h.z = hist[i + 2] * inv;
        h.w = hist[i + 3] * inv;
        pv[j] = h;                           // 16B-aligned global_store_dwordx4
    }
    for (int i = head + (nv << 2) + tid; i < hi; i += BLK)
        po[i] = hist[i] * inv;
}

extern "C" void kernel_launch(void* const* d_in, const int* in_sizes, int n_in,
                              void* d_out, int out_size, void* d_ws, size_t ws_size,
                              hipStream_t stream) {
    const int*   asg = (const int*)d_in[0];
    const float* w   = (const float*)d_in[1];
    float*       out = (float*)d_out;

    const int B = out_size / VOCAB;          // 512
    const int S = in_sizes[0] / B;           // 2048

    XTermFrequency_5471788335935_kernel<<<B * NCH, BLK, 0, stream>>>(
        asg, w, out, S, B);
}